// Round 8
// baseline (132.588 us; speedup 1.0000x reference)
//
#include <hip/hip_runtime.h>

typedef float f32x4 __attribute__((ext_vector_type(4)));
typedef short bf16x8 __attribute__((ext_vector_type(8)));   // 8 bf16 in 4 VGPRs (MFMA A/B operand)
typedef short bf16x4 __attribute__((ext_vector_type(4)));   // 4 bf16 in 2 VGPRs (16x16x16 operand)
typedef unsigned short u16x4 __attribute__((ext_vector_type(4)));

#define NS 8192
#define NB 16
#define NE 128
#define GS 4   // s-values per block (two waves per s)
// log2(e)/sqrt(8192), folded into Wk/bk by the prelude
#define SCALE_K (1.4426950408889634f / 90.50966799187809f)

// K=16 scores MFMA (no zero-padding waste) if the legacy builtin exists on this ROCm.
#if __has_builtin(__builtin_amdgcn_mfma_f32_16x16x16bf16_1k)
#define HAS_MFMA16 1
#else
#define HAS_MFMA16 0
#endif

// Pack two f32 -> two bf16 RNE-ish (round-half-up via +0x8000; perm takes high halves).
__device__ __forceinline__ unsigned pack_bf16_rn(float lo, float hi) {
  union { float f; unsigned u; } a, b; a.f = lo; b.f = hi;
  return __builtin_amdgcn_perm(b.u + 0x8000u, a.u + 0x8000u, 0x07060302u);
}
// Truncating pack (bias cancels in p/l since l is summed from these same bf16 values)
__device__ __forceinline__ unsigned pack_bf16_tr(float lo, float hi) {
  union { float f; unsigned u; } a, b; a.f = lo; b.f = hi;
  return __builtin_amdgcn_perm(b.u, a.u, 0x07060302u);
}
__device__ __forceinline__ bf16x8 frag_from_f32(const float* p) {
  f32x4 lo = *(const f32x4*)p;
  f32x4 hi = *(const f32x4*)(p + 4);
  union { bf16x8 v; unsigned u[4]; } r;
  r.u[0] = pack_bf16_rn(lo[0], lo[1]);
  r.u[1] = pack_bf16_rn(lo[2], lo[3]);
  r.u[2] = pack_bf16_rn(hi[0], hi[1]);
  r.u[3] = pack_bf16_rn(hi[2], hi[3]);
  return r.v;
}
__device__ __forceinline__ u16x4 pack4_rn(f32x4 v) {
  union { u16x4 s; unsigned u[2]; } r;
  r.u[0] = pack_bf16_rn(v[0], v[1]);
  r.u[1] = pack_bf16_rn(v[2], v[3]);
  return r.s;
}
__device__ __forceinline__ u16x4 pack4_tr(f32x4 v) {
  union { u16x4 s; unsigned u[2]; } r;
  r.u[0] = pack_bf16_tr(v[0], v[1]);
  r.u[1] = pack_bf16_tr(v[2], v[3]);
  return r.s;
}

// ---------- prelude: W -> bf16 fragments in d_ws (once per launch) ----------
// wsW layout: [mat(2)][ntile(8)][ks(4)][lane(64)][8 shorts]  -> frag load = 1 coalesced b128
// Wk, bk pre-scaled by SCALE_K so softmax is exp2(score) with no per-element multiply.
__global__ __launch_bounds__(256)
void nsa_prep(const float* __restrict__ Wk, const float* __restrict__ bk,
              const float* __restrict__ Wv, const float* __restrict__ bv,
              unsigned short* __restrict__ wsW, float* __restrict__ wsB)
{
  const int t    = blockIdx.x * 256 + threadIdx.x;   // 0..4095
  const int lane = t & 63, ks = (t >> 6) & 3, nt = (t >> 8) & 7, mat = (t >> 11) & 1;
  const int q = lane >> 4, ln = lane & 15;
  const float sc = mat ? 1.0f : SCALE_K;
  const float* W = (mat ? Wv : Wk) + (nt * 16 + ln) * NE + ks * 32 + q * 8;
  union { bf16x8 v; unsigned u[4]; } r;
  #pragma unroll
  for (int i = 0; i < 4; ++i)
    r.u[i] = pack_bf16_rn(W[2 * i] * sc, W[2 * i + 1] * sc);
  *(bf16x8*)(wsW + t * 8) = r.v;
  if (t < NE)          wsB[t] = bk[t] * SCALE_K;
  else if (t < 2 * NE) wsB[t] = bv[t - NE];
}

// ---------- main fused kernel ----------
// 8 waves/block (R5 structure). This round:
// (1) eb loop software-pipelined at mt-pair granularity: compute pair k+1
//     (scores MFMA + exp2 + pack, register-only) BEFORE reading P-pair k,
//     write pair k+1 AFTER the PV of pair k -> each ds_read waits only on
//     2 writes issued ~70 VALU-cycles earlier (was: 8 writes -> full wait -> 4 reads).
// (2) scores use K=16 mfma_16x16x16_bf16 when available (b=16 exactly; no
//     zero-pad waste, vf/kf frags b64, zbuf dead). Fallback = old K=32 path.
// (3) setprio dropped (R7: neutral).
__global__ __launch_bounds__(512, 4)
void nsa_fused(const float* __restrict__ x,
               const unsigned short* __restrict__ wsW,
               const float* __restrict__ wsB,
               float* __restrict__ out)
{
  // Kt/Vt: [mat(2)][s(GS)][e(128)][16 shorts] bf16, 16B-granule XOR swizzle per row.
  __shared__ __align__(16) unsigned short kt[2 * GS * NE * 16];   // 32 KiB
  __shared__ __align__(16) unsigned short xs[GS * NB * NE];       // 16 KiB x-stage (bf16)
  __shared__ __align__(16) unsigned short zbuf[32];               // 64B zeros (fallback K-pad)

  const int tid  = threadIdx.x;
  const int wave = tid >> 6;          // 0..7
  const int lane = tid & 63;
  const int q    = lane >> 4;
  const int ln   = lane & 15;
  const int g    = (ln >> 2) & 1;     // kt swizzle group bit
  const int s0   = blockIdx.x * GS;
  const int smt  = wave & 3;          // s this wave stages/attends
  const int h    = wave >> 2;         // 0: rows b 0-7 & eb 0-3;  1: rows b 8-15 & eb 4-7

  if (tid < 32) zbuf[tid] = 0;

  // ---------------- x staging: global -> bf16 -> xs (once per block) ----------------
  // xs layout: [s(4)][b(16)][granule gr=((ks*4+q)^b)&15][8 shorts]
  {
    const int c  = lane >> 5;          // 0..1 -> e-half
    const int sq = (lane >> 3) & 3;    // target-frag q
    const int bl = lane & 7;
    const int b  = h * 8 + bl;
    const float* xp = x + ((s0 + smt) * NB + b) * NE + c * 64 + sq * 8;
    #pragma unroll
    for (int ksp = 0; ksp < 2; ++ksp) {
      const int ks = c * 2 + ksp;
      bf16x8 v = frag_from_f32(xp + ksp * 32);
      const int gr = ((ks * 4 + sq) ^ b) & 15;
      *(bf16x8*)&xs[smt * 2048 + b * 128 + gr * 8] = v;
    }
  }
  __syncthreads();

  bf16x8 xf[4];   // ends as own-s A-frags (mt order ends at smt)

  // ---------------- KV phase ----------------
  {
    bf16x8 wf[2][4];   // nt = wave: 8 weight frags, single b128 loads
    float  bias[2];
    #pragma unroll
    for (int mat = 0; mat < 2; ++mat) {
      #pragma unroll
      for (int ks = 0; ks < 4; ++ks)
        wf[mat][ks] = *(const bf16x8*)(wsW + (((mat * 8 + wave) * 4 + ks) * 64 + lane) * 8);
      bias[mat] = wsB[mat * NE + wave * 16 + ln];
    }

    const int o = (((q >> 1) ^ g) << 3) + ((q & 1) << 2);   // kt swizzled 8B-write offset
    const int e = wave * 16 + ln;
    #pragma unroll
    for (int i = 0; i < GS; ++i) {
      const int mt = (smt + 1 + i) & (GS - 1);     // end at mt==smt so xf == own-s frags
      #pragma unroll
      for (int ks = 0; ks < 4; ++ks) {
        const int gr = ((ks * 4 + q) ^ ln) & 15;
        xf[ks] = *(const bf16x8*)&xs[mt * 2048 + ln * 128 + gr * 8];
      }
      #pragma unroll
      for (int mat = 0; mat < 2; ++mat) {
        f32x4 acc = { bias[mat], bias[mat], bias[mat], bias[mat] };
        #pragma unroll
        for (int ks = 0; ks < 4; ++ks)
          acc = __builtin_amdgcn_mfma_f32_16x16x32_bf16(xf[ks], wf[mat][ks], acc, 0, 0, 0);
        *(u16x4*)&kt[((mat * GS + mt) * NE + e) * 16 + o] = pack4_rn(acc);
      }
    }
  }
  __syncthreads();

  // ---------------- attention operand loads ----------------
#if HAS_MFMA16
  // b64 sub-row offset: granule (q>>1)^g, half (q&1)  -> K[b=q*4..+3][row]
  const int ov = (((q >> 1) ^ g) << 3) + ((q & 1) << 2);
  bf16x4 vf[8];                       // A[m=f(=ln)][k=b=q*4+i]
  #pragma unroll
  for (int mt = 0; mt < 8; ++mt)
    vf[mt] = *(const bf16x4*)&kt[((GS + smt) * NE + mt * 16 + ln) * 16 + ov];
  bf16x4 kcs[4];                      // B[k=b=q*4+i][n=e(=ln)] per eb
  #pragma unroll
  for (int e2 = 0; e2 < 4; ++e2)
    kcs[e2] = *(const bf16x4*)&kt[(smt * NE + (h * 4 + e2) * 16 + ln) * 16 + ov];
#else
  const int ro = ((q ^ g) & 1) << 3;  // kt swizzled 16B-read offset within row
  bf16x8 vf[8];                       // k>=16 zero-padded via zbuf
  #pragma unroll
  for (int mt = 0; mt < 8; ++mt) {
    const unsigned short* src =
        (q < 2) ? &kt[((GS + smt) * NE + mt * 16 + ln) * 16 + ro] : zbuf;
    vf[mt] = *(const bf16x8*)src;
  }
  bf16x8 kcs[4];                      // k>=16 don't-care (A zero there)
  #pragma unroll
  for (int e2 = 0; e2 < 4; ++e2)
    kcs[e2] = *(const bf16x8*)&kt[(smt * NE + (h * 4 + e2) * 16 + ln) * 16 + ro];
#endif
  __syncthreads();   // V slice / xs about to be overwritten with P

  // ---------------- attention phase: wave handles eb = h*4 .. h*4+3 ----------------
  {
    const int sw = s0 + smt;
    unsigned short* pw = h ? &xs[smt * 2048] : &kt[(GS + smt) * NE * 16];

    // all-ones A-frag: D[m][e] = sum_f P[e][f] -> softmax denominator on the MFMA pipe
    union { bf16x8 v; unsigned u[4]; } onesu;
    #pragma unroll
    for (int i = 0; i < 4; ++i) onesu.u[i] = 0x3F803F80u;   // bf16 1.0 pairs
    const bf16x8 ones = onesu.v;

    #pragma unroll
    for (int ebi = 0; ebi < 4; ++ebi) {
      const int eb = h * 4 + ebi;

      u16x4 ppa, ppb;   // packed P for the pending pair (registers only)

      // compute pair kp (scores MFMA -> exp2 -> pack), no LDS traffic
      auto comp = [&](int kp) {
        #pragma unroll
        for (int t = 0; t < 2; ++t) {
          const int mt = kp * 2 + t;
          const f32x4 z = { 0.f, 0.f, 0.f, 0.f };
#if HAS_MFMA16
          f32x4 sc = __builtin_amdgcn_mfma_f32_16x16x16bf16_1k(vf[mt], kcs[ebi], z, 0, 0, 0);
#else
          f32x4 sc = __builtin_amdgcn_mfma_f32_16x16x32_bf16(vf[mt], kcs[ebi], z, 0, 0, 0);
#endif
          f32x4 p;
          #pragma unroll
          for (int r = 0; r < 4; ++r) p[r] = __builtin_amdgcn_exp2f(sc[r]);
          if (t) ppb = pack4_tr(p); else ppa = pack4_tr(p);
        }
      };
      // write pair kp: P storage col = granule ((2mt|q>>1)^ln)&15, half (q&1)
      auto wr = [&](int kp) {
        #pragma unroll
        for (int t = 0; t < 2; ++t) {
          const int mt = kp * 2 + t;
          const int cw = ((q & 1) << 2) | (((((mt << 1) | (q >> 1)) ^ ln) & 15) << 3);
          *(u16x4*)&pw[ln * 128 + cw] = t ? ppb : ppa;
        }
      };

      comp(0); wr(0);
      f32x4 oacc = { 0.f, 0.f, 0.f, 0.f };
      f32x4 lacc = { 0.f, 0.f, 0.f, 0.f };
      #pragma unroll
      for (int k = 0; k < 4; ++k) {
        if (k < 3) comp(k + 1);                       // hides pair-k write latency
        const int cr = ((((k << 2) | q) ^ ln) & 15) << 3;
        const bf16x8 pf = *(const bf16x8*)&pw[ln * 128 + cr];
        oacc = __builtin_amdgcn_mfma_f32_16x16x32_bf16(xf[k], pf, oacc, 0, 0, 0);
        lacc = __builtin_amdgcn_mfma_f32_16x16x32_bf16(ones,  pf, lacc, 0, 0, 0);
        if (k < 3) wr(k + 1);                         // lands during next comp
      }
      const float inv_l = __builtin_amdgcn_rcpf(lacc[0]);   // D col = ln -> lane-matched
      const int e = eb * 16 + ln;
      #pragma unroll
      for (int r = 0; r < 4; ++r)
        out[(sw * NB + q * 4 + r) * NE + e] = oacc[r] * inv_l;
    }
  }
}

extern "C" void kernel_launch(void* const* d_in, const int* in_sizes, int n_in,
                              void* d_out, int out_size, void* d_ws, size_t ws_size,
                              hipStream_t stream)
{
  const float* x  = (const float*)d_in[0];
  const float* Wk = (const float*)d_in[1];
  const float* bk = (const float*)d_in[2];
  const float* Wv = (const float*)d_in[3];
  const float* bv = (const float*)d_in[4];
  float* o = (float*)d_out;

  unsigned short* wsW = (unsigned short*)d_ws;                  // 64 KiB
  float*          wsB = (float*)((char*)d_ws + 64 * 1024);      // 1 KiB

  hipLaunchKernelGGL(nsa_prep, dim3(16), dim3(256), 0, stream, Wk, bk, Wv, bv, wsW, wsB);
  hipLaunchKernelGGL(nsa_fused, dim3(NS / GS), dim3(512), 0, stream, x, wsW, wsB, o);
}

// Round 9
// 132.197 us; speedup vs baseline: 1.0030x; 1.0030x over previous
//
#include <hip/hip_runtime.h>

typedef float f32x4 __attribute__((ext_vector_type(4)));
typedef short bf16x8 __attribute__((ext_vector_type(8)));   // 8 bf16 in 4 VGPRs (MFMA A/B operand)
typedef short bf16x4 __attribute__((ext_vector_type(4)));   // 4 bf16 in 2 VGPRs (16x16x16 operand)
typedef unsigned short u16x4 __attribute__((ext_vector_type(4)));

#define NS 8192
#define NB 16
#define NE 128
#define GS 4   // s-values per block (two waves per s)
// log2(e)/sqrt(8192), folded into Wk/bk by the prelude
#define SCALE_K (1.4426950408889634f / 90.50966799187809f)

// K=16 scores MFMA (no zero-padding waste) if the legacy builtin exists on this ROCm.
#if __has_builtin(__builtin_amdgcn_mfma_f32_16x16x16bf16_1k)
#define HAS_MFMA16 1
#else
#define HAS_MFMA16 0
#endif

// Pack two f32 -> two bf16 RNE-ish (round-half-up via +0x8000; perm takes high halves).
__device__ __forceinline__ unsigned pack_bf16_rn(float lo, float hi) {
  union { float f; unsigned u; } a, b; a.f = lo; b.f = hi;
  return __builtin_amdgcn_perm(b.u + 0x8000u, a.u + 0x8000u, 0x07060302u);
}
// Truncating pack (bias cancels in p/l since l is summed from these same bf16 values)
__device__ __forceinline__ unsigned pack_bf16_tr(float lo, float hi) {
  union { float f; unsigned u; } a, b; a.f = lo; b.f = hi;
  return __builtin_amdgcn_perm(b.u, a.u, 0x07060302u);
}
__device__ __forceinline__ bf16x8 frag_from_f32(const float* p) {
  f32x4 lo = *(const f32x4*)p;
  f32x4 hi = *(const f32x4*)(p + 4);
  union { bf16x8 v; unsigned u[4]; } r;
  r.u[0] = pack_bf16_rn(lo[0], lo[1]);
  r.u[1] = pack_bf16_rn(lo[2], lo[3]);
  r.u[2] = pack_bf16_rn(hi[0], hi[1]);
  r.u[3] = pack_bf16_rn(hi[2], hi[3]);
  return r.v;
}
__device__ __forceinline__ u16x4 pack4_rn(f32x4 v) {
  union { u16x4 s; unsigned u[2]; } r;
  r.u[0] = pack_bf16_rn(v[0], v[1]);
  r.u[1] = pack_bf16_rn(v[2], v[3]);
  return r.s;
}
__device__ __forceinline__ u16x4 pack4_tr(f32x4 v) {
  union { u16x4 s; unsigned u[2]; } r;
  r.u[0] = pack_bf16_tr(v[0], v[1]);
  r.u[1] = pack_bf16_tr(v[2], v[3]);
  return r.s;
}

// ---------- prelude: W -> bf16 fragments in d_ws (once per launch) ----------
// wsW layout: [mat(2)][ntile(8)][ks(4)][lane(64)][8 shorts]  -> frag load = 1 coalesced b128
// Wk, bk pre-scaled by SCALE_K so softmax is exp2(score) with no per-element multiply.
__global__ __launch_bounds__(256)
void nsa_prep(const float* __restrict__ Wk, const float* __restrict__ bk,
              const float* __restrict__ Wv, const float* __restrict__ bv,
              unsigned short* __restrict__ wsW, float* __restrict__ wsB)
{
  const int t    = blockIdx.x * 256 + threadIdx.x;   // 0..4095
  const int lane = t & 63, ks = (t >> 6) & 3, nt = (t >> 8) & 7, mat = (t >> 11) & 1;
  const int q = lane >> 4, ln = lane & 15;
  const float sc = mat ? 1.0f : SCALE_K;
  const float* W = (mat ? Wv : Wk) + (nt * 16 + ln) * NE + ks * 32 + q * 8;
  union { bf16x8 v; unsigned u[4]; } r;
  #pragma unroll
  for (int i = 0; i < 4; ++i)
    r.u[i] = pack_bf16_rn(W[2 * i] * sc, W[2 * i + 1] * sc);
  *(bf16x8*)(wsW + t * 8) = r.v;
  if (t < NE)          wsB[t] = bk[t] * SCALE_K;
  else if (t < 2 * NE) wsB[t] = bv[t - NE];
}

// ---------- main fused kernel ----------
// 8 waves/block (R5 structure). This round (T15 att[2] double-pipeline):
// the ENTIRE scores+exp2+pack of eb i+1 runs register-only BETWEEN the P-write
// and the P-read/PV of eb i. Write->read LDS latency and exp2 latency are
// covered by independent MFMA/VALU work; PV MFMAs co-issue with next eb's exp2.
// Per-wave LDS P buffer stays single (in-order per-wave DS queue: the write of
// eb i+1, issued after eb i's reads, cannot overtake them).
__global__ __launch_bounds__(512, 4)
void nsa_fused(const float* __restrict__ x,
               const unsigned short* __restrict__ wsW,
               const float* __restrict__ wsB,
               float* __restrict__ out)
{
  // Kt/Vt: [mat(2)][s(GS)][e(128)][16 shorts] bf16, 16B-granule XOR swizzle per row.
  __shared__ __align__(16) unsigned short kt[2 * GS * NE * 16];   // 32 KiB
  __shared__ __align__(16) unsigned short xs[GS * NB * NE];       // 16 KiB x-stage (bf16)
#if !HAS_MFMA16
  __shared__ __align__(16) unsigned short zbuf[32];               // 64B zeros (K-pad)
#endif

  const int tid  = threadIdx.x;
  const int wave = tid >> 6;          // 0..7
  const int lane = tid & 63;
  const int q    = lane >> 4;
  const int ln   = lane & 15;
  const int g    = (ln >> 2) & 1;     // kt swizzle group bit
  const int s0   = blockIdx.x * GS;
  const int smt  = wave & 3;          // s this wave stages/attends
  const int h    = wave >> 2;         // 0: rows b 0-7 & eb 0-3;  1: rows b 8-15 & eb 4-7

#if !HAS_MFMA16
  if (tid < 32) zbuf[tid] = 0;
#endif

  // ---------------- x staging: global -> bf16 -> xs (once per block) ----------------
  // xs layout: [s(4)][b(16)][granule gr=((ks*4+q)^b)&15][8 shorts]
  {
    const int c  = lane >> 5;          // 0..1 -> e-half
    const int sq = (lane >> 3) & 3;    // target-frag q
    const int bl = lane & 7;
    const int b  = h * 8 + bl;
    const float* xp = x + ((s0 + smt) * NB + b) * NE + c * 64 + sq * 8;
    #pragma unroll
    for (int ksp = 0; ksp < 2; ++ksp) {
      const int ks = c * 2 + ksp;
      bf16x8 v = frag_from_f32(xp + ksp * 32);
      const int gr = ((ks * 4 + sq) ^ b) & 15;
      *(bf16x8*)&xs[smt * 2048 + b * 128 + gr * 8] = v;
    }
  }
  __syncthreads();

  bf16x8 xf[4];   // ends as own-s A-frags (mt order ends at smt)

  // ---------------- KV phase ----------------
  {
    bf16x8 wf[2][4];   // nt = wave: 8 weight frags, single b128 loads
    float  bias[2];
    #pragma unroll
    for (int mat = 0; mat < 2; ++mat) {
      #pragma unroll
      for (int ks = 0; ks < 4; ++ks)
        wf[mat][ks] = *(const bf16x8*)(wsW + (((mat * 8 + wave) * 4 + ks) * 64 + lane) * 8);
      bias[mat] = wsB[mat * NE + wave * 16 + ln];
    }

    const int o = (((q >> 1) ^ g) << 3) + ((q & 1) << 2);   // kt swizzled 8B-write offset
    const int e = wave * 16 + ln;
    #pragma unroll
    for (int i = 0; i < GS; ++i) {
      const int mt = (smt + 1 + i) & (GS - 1);     // end at mt==smt so xf == own-s frags
      #pragma unroll
      for (int ks = 0; ks < 4; ++ks) {
        const int gr = ((ks * 4 + q) ^ ln) & 15;
        xf[ks] = *(const bf16x8*)&xs[mt * 2048 + ln * 128 + gr * 8];
      }
      #pragma unroll
      for (int mat = 0; mat < 2; ++mat) {
        f32x4 acc = { bias[mat], bias[mat], bias[mat], bias[mat] };
        #pragma unroll
        for (int ks = 0; ks < 4; ++ks)
          acc = __builtin_amdgcn_mfma_f32_16x16x32_bf16(xf[ks], wf[mat][ks], acc, 0, 0, 0);
        *(u16x4*)&kt[((mat * GS + mt) * NE + e) * 16 + o] = pack4_rn(acc);
      }
    }
  }
  __syncthreads();

  // ---------------- attention operand loads ----------------
#if HAS_MFMA16
  // b64 sub-row offset: granule (q>>1)^g, half (q&1)  -> K[b=q*4..+3][row]
  const int ov = (((q >> 1) ^ g) << 3) + ((q & 1) << 2);
  bf16x4 vf[8];                       // A[m=f(=ln)][k=b=q*4+i]
  #pragma unroll
  for (int mt = 0; mt < 8; ++mt)
    vf[mt] = *(const bf16x4*)&kt[((GS + smt) * NE + mt * 16 + ln) * 16 + ov];
  bf16x4 kcs[4];                      // B[k=b=q*4+i][n=e(=ln)] per eb
  #pragma unroll
  for (int e2 = 0; e2 < 4; ++e2)
    kcs[e2] = *(const bf16x4*)&kt[(smt * NE + (h * 4 + e2) * 16 + ln) * 16 + ov];
#else
  const int ro = ((q ^ g) & 1) << 3;  // kt swizzled 16B-read offset within row
  bf16x8 vf[8];                       // k>=16 zero-padded via zbuf
  #pragma unroll
  for (int mt = 0; mt < 8; ++mt) {
    const unsigned short* src =
        (q < 2) ? &kt[((GS + smt) * NE + mt * 16 + ln) * 16 + ro] : zbuf;
    vf[mt] = *(const bf16x8*)src;
  }
  bf16x8 kcs[4];                      // k>=16 don't-care (A zero there)
  #pragma unroll
  for (int e2 = 0; e2 < 4; ++e2)
    kcs[e2] = *(const bf16x8*)&kt[(smt * NE + (h * 4 + e2) * 16 + ln) * 16 + ro];
#endif
  __syncthreads();   // V slice / xs about to be overwritten with P

  // ---------------- attention phase: eb = h*4 .. h*4+3, 2-deep pipelined ----------------
  {
    const int sw = s0 + smt;
    unsigned short* pw = h ? &xs[smt * 2048] : &kt[(GS + smt) * NE * 16];

    // all-ones A-frag: D[m][e] = sum_f P[e][f] -> softmax denominator on the MFMA pipe
    union { bf16x8 v; unsigned u[4]; } onesu;
    #pragma unroll
    for (int i = 0; i < 4; ++i) onesu.u[i] = 0x3F803F80u;   // bf16 1.0 pairs
    const bf16x8 ones = onesu.v;

    u16x4 pA[8], pB[8];   // packed P for two ebs (16 VGPR each) -- static indexing only

    // scores+exp2+pack for slot ebi -> pp[8], register-only (no LDS)
    auto comp = [&](int ebi, u16x4* pp) {
      #pragma unroll
      for (int mt = 0; mt < 8; ++mt) {
        const f32x4 z = { 0.f, 0.f, 0.f, 0.f };
#if HAS_MFMA16
        f32x4 sc = __builtin_amdgcn_mfma_f32_16x16x16bf16_1k(vf[mt], kcs[ebi], z, 0, 0, 0);
#else
        f32x4 sc = __builtin_amdgcn_mfma_f32_16x16x32_bf16(vf[mt], kcs[ebi], z, 0, 0, 0);
#endif
        f32x4 p;
        #pragma unroll
        for (int r = 0; r < 4; ++r) p[r] = __builtin_amdgcn_exp2f(sc[r]);
        pp[mt] = pack4_tr(p);
      }
    };
    // P-write: storage col = granule ((2mt|q>>1)^ln)&15, half (q&1)
    auto wr = [&](const u16x4* pp) {
      #pragma unroll
      for (int mt = 0; mt < 8; ++mt) {
        const int cw = ((q & 1) << 2) | (((((mt << 1) | (q >> 1)) ^ ln) & 15) << 3);
        *(u16x4*)&pw[ln * 128 + cw] = pp[mt];
      }
    };
    // PV + denominator + store for slot ebi (reads P from LDS)
    auto pv = [&](int ebi) {
      f32x4 oacc = { 0.f, 0.f, 0.f, 0.f };
      f32x4 lacc = { 0.f, 0.f, 0.f, 0.f };
      #pragma unroll
      for (int k = 0; k < 4; ++k) {
        const int cr = ((((k << 2) | q) ^ ln) & 15) << 3;
        const bf16x8 pf = *(const bf16x8*)&pw[ln * 128 + cr];
        oacc = __builtin_amdgcn_mfma_f32_16x16x32_bf16(xf[k], pf, oacc, 0, 0, 0);
        lacc = __builtin_amdgcn_mfma_f32_16x16x32_bf16(ones,  pf, lacc, 0, 0, 0);
      }
      const float inv_l = __builtin_amdgcn_rcpf(lacc[0]);   // D col = ln -> lane-matched
      const int e = (h * 4 + ebi) * 16 + ln;
      #pragma unroll
      for (int r = 0; r < 4; ++r)
        out[(sw * NB + q * 4 + r) * NE + e] = oacc[r] * inv_l;
    };

    // 2-deep schedule: comp(i+1) fills the write->read gap of pv(i);
    // wr(i+1) issues after pv(i)'s reads (in-order DS => no hazard).
    comp(0, pA);
    wr(pA);
    comp(1, pB);
    pv(0);
    wr(pB);
    comp(2, pA);
    pv(1);
    wr(pA);
    comp(3, pB);
    pv(2);
    wr(pB);
    pv(3);
  }
}

extern "C" void kernel_launch(void* const* d_in, const int* in_sizes, int n_in,
                              void* d_out, int out_size, void* d_ws, size_t ws_size,
                              hipStream_t stream)
{
  const float* x  = (const float*)d_in[0];
  const float* Wk = (const float*)d_in[1];
  const float* bk = (const float*)d_in[2];
  const float* Wv = (const float*)d_in[3];
  const float* bv = (const float*)d_in[4];
  float* o = (float*)d_out;

  unsigned short* wsW = (unsigned short*)d_ws;                  // 64 KiB
  float*          wsB = (float*)((char*)d_ws + 64 * 1024);      // 1 KiB

  hipLaunchKernelGGL(nsa_prep, dim3(16), dim3(256), 0, stream, Wk, bk, Wv, bv, wsW, wsB);
  hipLaunchKernelGGL(nsa_fused, dim3(NS / GS), dim3(512), 0, stream, x, wsW, wsB, o);
}